// Round 12
// baseline (193.039 us; speedup 1.0000x reference)
//
#include <hip/hip_runtime.h>

#define BB 2
#define SS 4096
#define DD 768
#define HH 12
#define HDD 64
#define W1C 256
#define NCC 16
#define GG 8

typedef unsigned short u16;
typedef __attribute__((ext_vector_type(4))) unsigned short u16x4;
typedef __attribute__((ext_vector_type(8))) unsigned short u16x8;
typedef __attribute__((ext_vector_type(8))) short s16x8;
typedef __attribute__((ext_vector_type(4))) float f32x4;

__device__ __forceinline__ float b2f(u16 u) {
  union { unsigned int i; float f; } v;
  v.i = ((unsigned int)u) << 16;
  return v.f;
}
__device__ __forceinline__ u16 f2b(float f) {
  union { float f; unsigned int i; } v;
  v.f = f;
  unsigned int r = v.i + 0x7FFFu + ((v.i >> 16) & 1u);
  return (u16)(r >> 16);
}
__device__ __forceinline__ float fexp2(float x) {
#if __has_builtin(__builtin_amdgcn_exp2f)
  return __builtin_amdgcn_exp2f(x);
#else
  return exp2f(x);
#endif
}
__device__ __forceinline__ unsigned pk_bf16(float lo, float hi) {
  unsigned r;
  asm("v_cvt_pk_bf16_f32 %0, %1, %2" : "=v"(r) : "v"(lo), "v"(hi));
  return r;
}
__device__ __forceinline__ void load_lds16(const void* g, void* l) {
  __builtin_amdgcn_global_load_lds(
      (const __attribute__((address_space(1))) unsigned int*)g,
      (__attribute__((address_space(3))) unsigned int*)l, 16, 0, 0);
}

#define QSCALE 0.18033688011112042f  // 0.125 * log2(e)

// ---------------------------------------------------------------------------
// Fused prep: blockIdx dispatch. (unchanged)
// ---------------------------------------------------------------------------
struct WtArgs { const float* W[6]; };

__global__ __launch_bounds__(256) void prep(
    const float* __restrict__ hs, WtArgs wa, const float* __restrict__ Wqg,
    const float* __restrict__ bqg, u16* __restrict__ Ab,
    u16* __restrict__ WT, u16* __restrict__ QG) {
  __shared__ __align__(16) char pshm[24576];
  const int bid = blockIdx.x;
  const int t = threadIdx.x;

  if (bid < 3072) {
    int i = bid * 256 + t;
    const float4* p = (const float4*)(hs + (size_t)i * 8);
    float4 a = p[0], b = p[1];
    u16x8 o;
    o[0] = f2b(a.x); o[1] = f2b(a.y); o[2] = f2b(a.z); o[3] = f2b(a.w);
    o[4] = f2b(b.x); o[5] = f2b(b.y); o[6] = f2b(b.z); o[7] = f2b(b.w);
    *(u16x8*)(Ab + (size_t)i * 8) = o;
  } else if (bid < 3936) {
    float (*T)[65] = (float (*)[65])pshm;
    const int t2 = bid - 3072;
    const int mat = t2 / 144;
    const int rem = t2 % 144;
    const int k0 = (rem / 12) * 64;
    const int n0 = (rem % 12) * 64;
    const float* __restrict__ W = wa.W[mat];
#pragma unroll
    for (int i = 0; i < 4; i++) {
      int idx4 = t + i * 256;
      int r = idx4 >> 4, c4 = idx4 & 15;
      float4 v = *(const float4*)(W + (size_t)(k0 + r) * 768 + n0 + c4 * 4);
      T[r][c4 * 4 + 0] = v.x; T[r][c4 * 4 + 1] = v.y;
      T[r][c4 * 4 + 2] = v.z; T[r][c4 * 4 + 3] = v.w;
    }
    __syncthreads();
#pragma unroll
    for (int i = 0; i < 2; i++) {
      int ci = t + i * 256;
      int nl = ci >> 3, k8 = ci & 7;
      u16x8 o;
#pragma unroll
      for (int jj = 0; jj < 8; jj++) o[jj] = f2b(T[k8 * 8 + jj][nl]);
      *(u16x8*)(WT + ((size_t)mat * 768 + n0 + nl) * 768 + k0 + k8 * 8) = o;
    }
  } else {
    float (*hsL)[768] = (float (*)[768])pshm;
    const int bh = bid - 3936;
    const int b = bh / HH, h = bh % HH;
#pragma unroll
    for (int i = 0; i < 6; i++) {
      int idx = t + i * 256;
      int row = idx / 192, c4 = idx % 192;
      *(float4*)&hsL[row][c4 * 4] =
          *(const float4*)(hs + ((size_t)b * SS + row) * DD + c4 * 4);
    }
    __syncthreads();
#pragma unroll
    for (int rep = 0; rep < 2; rep++) {
      int qi = rep * 4 + (t >> 6);
      int d = t & 63, n = h * 64 + d;
      float acc = bqg[n];
      for (int k = 0; k < DD; k++)
        acc = fmaf(hsL[qi][k], Wqg[(size_t)k * DD + n], acc);
      QG[((size_t)bh * 16 + qi) * 64 + d] = f2b(acc * QSCALE);
    }
#pragma unroll
    for (int i = 0; i < 2; i++) {
      int idx = t + i * 256;
      int row = 8 + (idx >> 6), d = idx & 63;
      QG[((size_t)bh * 16 + row) * 64 + d] = 0;
    }
  }
}

struct BiasArgs { const float* bias[5]; };

// ---------------------------------------------------------------------------
// 8-phase 256x256 bf16 MFMA GEMM + coalesced LDS epilogue. (unchanged R11)
// ---------------------------------------------------------------------------
__global__ __launch_bounds__(512, 1) void gemm0_8p(
    const u16* __restrict__ A, const u16* __restrict__ WT, BiasArgs ba,
    u16* __restrict__ outb) {
  constexpr int NTL = 15;
  constexpr int NWG = 480;
  constexpr int NT = 12;
  constexpr int TBYTES = 256 * 64 * 2;
  constexpr int BUFB = 2 * TBYTES;
  constexpr int EPAD = 264;

  extern __shared__ __align__(16) char smem[];

  const int tid = threadIdx.x;
  const int w = tid >> 6, l = tid & 63;
  const int lq = l & 15, g = l >> 4;
  const int wm = w >> 2, wn = w & 3;

  const int cpx = NWG >> 3;
  const int id = (int)blockIdx.x;
  const int swz = (id & 7) * cpx + (id >> 3);
  const int bm = swz / NTL, bn = swz % NTL;
  const int m0 = bm * 256;
  const int nw0 = bn * 256;
  const int wsel = bn / 3;
  const int nmat0 = (bn % 3) * 256;
  const float* __restrict__ bias = ba.bias[wsel];

  f32x4 acc[8][4];
#pragma unroll
  for (int i = 0; i < 8; i++)
#pragma unroll
    for (int j = 0; j < 4; j++) acc[i][j] = (f32x4){0.f, 0.f, 0.f, 0.f};

  auto stageH = [&](int t, int mat, int h) {
    const int k0 = t * 64;
    char* dst = smem + (t & 1) * BUFB + mat * TBYTES + h * 16384;
    const u16* src = mat ? WT : A;
    const int rbase = (mat ? nw0 : m0) + h * 128;
#pragma unroll
    for (int j = 0; j < 2; j++) {
      const int p = (j * 8 + w) * 64 + l;
      const int row = p >> 3, sl = p & 7;
      load_lds16(src + (size_t)(rbase + row) * 768 + k0 +
                     ((sl ^ (row & 7)) * 8),
                 dst + (j * 8 + w) * 1024);
    }
  };

  stageH(0, 0, 0); stageH(0, 0, 1); stageH(0, 1, 0); stageH(0, 1, 1);
  stageH(1, 0, 0);
  asm volatile("s_waitcnt vmcnt(2)" ::: "memory");
  __builtin_amdgcn_sched_barrier(0);
  __builtin_amdgcn_s_barrier();
  __builtin_amdgcn_sched_barrier(0);

  s16x8 bf[4];

  for (int kt = 0; kt < NT; kt++) {
    const u16* rA = (const u16*)(smem + (kt & 1) * BUFB);
    const u16* rB = (const u16*)(smem + (kt & 1) * BUFB + TBYTES);

#pragma unroll
    for (int ph = 0; ph < 4; ph++) {
      const int mh = ph & 1;
      const int kh = ph >> 1;
      s16x8 af[4];
#pragma unroll
      for (int mi = 0; mi < 4; mi++) {
        const int r = wm * 128 + (mh * 4 + mi) * 16 + lq;
        af[mi] =
            *(const s16x8*)(rA + r * 64 + (((kh * 4 + g) ^ (r & 7)) * 8));
      }
      if (mh == 0) {
#pragma unroll
        for (int nj = 0; nj < 4; nj++) {
          const int r = wn * 64 + nj * 16 + lq;
          bf[nj] =
              *(const s16x8*)(rB + r * 64 + (((kh * 4 + g) ^ (r & 7)) * 8));
        }
      }
      if (ph == 0) { if (kt + 1 < NT) stageH(kt + 1, 0, 1); }
      else if (ph == 1) { if (kt + 1 < NT) stageH(kt + 1, 1, 0); }
      else if (ph == 2) { if (kt + 1 < NT) stageH(kt + 1, 1, 1); }
      else { if (kt + 2 < NT) stageH(kt + 2, 0, 0); }

      __builtin_amdgcn_s_barrier();
      asm volatile("s_waitcnt lgkmcnt(0)" ::: "memory");
      __builtin_amdgcn_sched_barrier(0);
      __builtin_amdgcn_s_setprio(1);
#pragma unroll
      for (int mi = 0; mi < 4; mi++)
#pragma unroll
        for (int nj = 0; nj < 4; nj++)
          acc[mh * 4 + mi][nj] = __builtin_amdgcn_mfma_f32_16x16x32_bf16(
              af[mi], bf[nj], acc[mh * 4 + mi][nj], 0, 0, 0);
      __builtin_amdgcn_s_setprio(0);

      if (ph == 3) {
        if (kt < NT - 2)
          asm volatile("s_waitcnt vmcnt(2)" ::: "memory");
        else
          asm volatile("s_waitcnt vmcnt(0)" ::: "memory");
      }
      __builtin_amdgcn_sched_barrier(0);
      __builtin_amdgcn_s_barrier();
      __builtin_amdgcn_sched_barrier(0);
    }
  }

  {
    const float scale = (wsel == 0) ? QSCALE : 1.0f;
    u16* T = (u16*)smem;
#pragma unroll
    for (int nj = 0; nj < 4; nj++) {
      const int cl = wn * 64 + nj * 16 + lq;
      const float bv = bias[nmat0 + cl];
#pragma unroll
      for (int mi = 0; mi < 8; mi++) {
#pragma unroll
        for (int r = 0; r < 4; r++) {
          const int ml = wm * 128 + mi * 16 + g * 4 + r;
          T[ml * EPAD + cl] = f2b((acc[mi][nj][r] + bv) * scale);
        }
      }
    }
    __syncthreads();
    u16* outw = outb + (size_t)wsel * ((size_t)BB * HH * SS * HDD);
    const int b = m0 >> 12;
    const int sbase = m0 & 4095;
    const int hbase = nmat0 >> 6;
#pragma unroll
    for (int j = 0; j < 16; j++) {
      const int slot = j * 512 + tid;
      const int seg = slot >> 3, part = slot & 7;
      const int h = seg >> 8, sl = seg & 255;
      u16x8 v = *(const u16x8*)(T + sl * EPAD + h * 64 + part * 8);
      *(u16x8*)(outw +
                ((size_t)(b * HH + hbase + h) * SS + sbase + sl) * HDD +
                part * 8) = v;
    }
  }
}

// ---------------------------------------------------------------------------
// bf16 MFMA GEMM, 3-buffer ring — Wo (MODE 1), coalesced fp32 epilogue.
// (unchanged R11)
// ---------------------------------------------------------------------------
template <int MODE>
__global__ __launch_bounds__(512, 1) void gemm_bf16(
    const u16* __restrict__ A, const u16* __restrict__ WT, BiasArgs ba,
    u16* __restrict__ outb, float* __restrict__ outf) {
  constexpr int NTL = (MODE == 0) ? 15 : 3;
  constexpr int NWG = 64 * NTL;
  constexpr int NT = 12;
  constexpr int ABYTES = 128 * 64 * 2;
  constexpr int BBYTES = 256 * 64 * 2;
  constexpr int BUFB = ABYTES + BBYTES;
  constexpr int EPADF = 260;

  extern __shared__ __align__(16) char smem[];

  const int tid = threadIdx.x;
  const int w = tid >> 6, l = tid & 63;
  const int lq = l & 15, g = l >> 4;
  const int wm = w >> 2, wn = w & 3;

  const int cpx = NWG >> 3;
  const int id = (int)blockIdx.x;
  const int swz = (id & 7) * cpx + (id >> 3);
  const int bm = swz / NTL, bn = swz % NTL;
  const int m0 = bm * 128;
  const int nw0 = bn * 256;
  const int wsel = (MODE == 0) ? (bn / 3) : 0;
  const int nmat0 = (MODE == 0) ? ((bn % 3) * 256) : (bn * 256);
  const float* __restrict__ bias = ba.bias[wsel];

  f32x4 acc[4][4];
#pragma unroll
  for (int i = 0; i < 4; i++)
#pragma unroll
    for (int j = 0; j < 4; j++) acc[i][j] = (f32x4){0.f, 0.f, 0.f, 0.f};

  auto stage = [&](int t) {
    const int k0 = t * 64;
    char* uA = smem + (t % 3) * BUFB;
    char* uB = uA + ABYTES;
#pragma unroll
    for (int j = 0; j < 2; j++) {
      const int ci = j * 8 + w;
      const int p = ci * 64 + l;
      const int row = p >> 3, sl = p & 7;
      load_lds16(A + (size_t)(m0 + row) * 768 + k0 + ((sl ^ (row & 7)) * 8),
                 uA + ci * 1024);
    }
#pragma unroll
    for (int j = 0; j < 4; j++) {
      const int ci = j * 8 + w;
      const int p = ci * 64 + l;
      const int row = p >> 3, sl = p & 7;
      load_lds16(WT + (size_t)(nw0 + row) * 768 + k0 + ((sl ^ (row & 7)) * 8),
                 uB + ci * 1024);
    }
  };

  stage(0);
  stage(1);
  asm volatile("s_waitcnt vmcnt(6)" ::: "memory");
  __builtin_amdgcn_sched_barrier(0);
  __builtin_amdgcn_s_barrier();
  __builtin_amdgcn_sched_barrier(0);

  for (int kt = 0; kt < NT; kt++) {
    const u16* rA = (const u16*)(smem + (kt % 3) * BUFB);
    const u16* rB = (const u16*)(smem + (kt % 3) * BUFB + ABYTES);

    if (kt < NT - 2) stage(kt + 2);
    __builtin_amdgcn_sched_barrier(0);

    s16x8 af[4][2], bf[4][2];
#pragma unroll
    for (int mi = 0; mi < 4; mi++) {
      const int r = wm * 64 + mi * 16 + lq;
#pragma unroll
      for (int ks = 0; ks < 2; ks++)
        af[mi][ks] =
            *(const s16x8*)(rA + r * 64 + (((ks * 4 + g) ^ (r & 7)) * 8));
    }
#pragma unroll
    for (int nj = 0; nj < 4; nj++) {
      const int r = wn * 64 + nj * 16 + lq;
#pragma unroll
      for (int ks = 0; ks < 2; ks++)
        bf[nj][ks] =
            *(const s16x8*)(rB + r * 64 + (((ks * 4 + g) ^ (r & 7)) * 8));
    }
#pragma unroll
    for (int mi = 0; mi < 4; mi++)
#pragma unroll
      for (int nj = 0; nj < 4; nj++)
#pragma unroll
        for (int ks = 0; ks < 2; ks++)
          acc[mi][nj] = __builtin_amdgcn_mfma_f32_16x16x32_bf16(
              af[mi][ks], bf[nj][ks], acc[mi][nj], 0, 0, 0);

    if (kt < NT - 2)
      asm volatile("s_waitcnt vmcnt(6)" ::: "memory");
    else
      asm volatile("s_waitcnt vmcnt(0)" ::: "memory");
    __builtin_amdgcn_sched_barrier(0);
    __builtin_amdgcn_s_barrier();
    __builtin_amdgcn_sched_barrier(0);
  }

  if (MODE == 0) {
    const float scale = (wsel == 0) ? QSCALE : 1.0f;
    u16* outw = outb + (size_t)wsel * ((size_t)BB * HH * SS * HDD);
#pragma unroll
    for (int nj = 0; nj < 4; nj++) {
      const int c = nmat0 + wn * 64 + nj * 16 + lq;
      const float bv = bias[c];
      const int h = c >> 6, hd = c & 63;
#pragma unroll
      for (int mi = 0; mi < 4; mi++) {
#pragma unroll
        for (int r = 0; r < 4; r++) {
          const int m = m0 + wm * 64 + mi * 16 + g * 4 + r;
          const int b = m >> 12, s = m & 4095;
          outw[((size_t)(b * HH + h) * SS + s) * HDD + hd] =
              f2b((acc[mi][nj][r] + bv) * scale);
        }
      }
    }
  } else {
    float* Tf = (float*)smem;
#pragma unroll
    for (int nj = 0; nj < 4; nj++) {
      const int cl = wn * 64 + nj * 16 + lq;
      const float bv = bias[nmat0 + cl];
#pragma unroll
      for (int mi = 0; mi < 4; mi++) {
#pragma unroll
        for (int r = 0; r < 4; r++) {
          const int ml = wm * 64 + mi * 16 + g * 4 + r;
          Tf[ml * EPADF + cl] = acc[mi][nj][r] + bv;
        }
      }
    }
    __syncthreads();
#pragma unroll
    for (int j = 0; j < 16; j++) {
      const int slot = j * 512 + tid;
      const int row = slot >> 6, part = slot & 63;
      float4 v = *(const float4*)(Tf + row * EPADF + part * 4);
      *(float4*)(outf + (size_t)(m0 + row) * 768 + nmat0 + part * 4) = v;
    }
  }
}

// ---------------------------------------------------------------------------
// Banded MFMA attention, pipelined. CHANGE vs R11: redundant end-of-loop
// barrier removed — per-wave lgkmcnt(0) before barrier-A already proves the
// previous tile's LDS reads drained; barrier-A alone serializes staging
// against readers (stage(t+1) and publish(t+1) both target the buffer whose
// readers finished before the PREVIOUS barrier-A).
// ---------------------------------------------------------------------------
__global__ __launch_bounds__(512, 4) void attn_band(
    const u16* __restrict__ Q, const u16* __restrict__ K,
    const u16* __restrict__ V, const int* __restrict__ amask,
    u16* __restrict__ ATT) {
  __shared__ __align__(16) char smem[32768];
  const int tid = threadIdx.x;
  const int w = tid >> 6, lane = tid & 63;
  const int lq = lane & 15, g = lane >> 4;
  const int h = blockIdx.y, b = blockIdx.z;
  const int bh = b * HH + h;
  const size_t bhs = (size_t)bh * SS;
  const int q0 = (int)blockIdx.x * 128;

  s16x8 qf[2];
  {
    const u16* qp = Q + (bhs + q0 + w * 16 + lq) * 64;
    qf[0] = *(const s16x8*)(qp + g * 8);
    qf[1] = *(const s16x8*)(qp + 32 + g * 8);
  }

  f32x4 oacc[4];
#pragma unroll
  for (int i = 0; i < 4; i++) oacc[i] = (f32x4){0.f, 0.f, 0.f, 0.f};
  float denom = 0.f;

  const int NT = 11;
  u16x8 vreg;

  auto jof = [&](int t) { return t < 10 ? q0 - 256 + t * 64 : 0; };

  auto stage_issue = [&](int t) {
    const int j0 = jof(t);
    char* Kb_ = smem + (t & 1) * 16384;
    const int row = tid >> 3, sl = tid & 7;
    if (j0 >= 0 && j0 + 64 <= SS) {
      load_lds16(K + (bhs + j0 + row) * 64 + ((sl ^ (row & 7)) * 8),
                 Kb_ + w * 1024);
    } else {
      int jj = j0 + row;
      u16x8 val;
#pragma unroll
      for (int e = 0; e < 8; e++) val[e] = 0;
      if ((unsigned)jj < (unsigned)SS)
        val = *(const u16x8*)(K + (bhs + jj) * 64 + ((sl ^ (row & 7)) * 8));
      *(u16x8*)(Kb_ + tid * 16) = val;
    }
    int jj = j0 + lane;
    u16x8 vv;
#pragma unroll
    for (int e = 0; e < 8; e++) vv[e] = 0;
    if ((unsigned)jj < (unsigned)SS)
      vv = *(const u16x8*)(V + (bhs + jj) * 64 + w * 8);
    vreg = vv;
  };

  stage_issue(0);

  for (int kt = 0; kt < NT; kt++) {
    const int j0 = jof(kt);
    const int cur = kt & 1;
    char* Kl = smem + cur * 16384;
    char* VT = Kl + 8192;
    const bool bandfree = (kt == 10);
    const int klimit = bandfree ? 8 : 64;

    int jm = j0 + lane;
    int mv = ((unsigned)jm < (unsigned)SS) ? amask[b * SS + jm] : -1;
    bool okk = (mv >= 0) && (lane < klimit);
    unsigned long long vm = __ballot(okk);

    asm volatile("s_waitcnt vmcnt(0)" ::: "memory");
#pragma unroll
    for (int e = 0; e < 8; e++)
      *(u16*)(VT + (w * 8 + e) * 128 + ((lane * 2) ^ (e << 4))) = vreg[e];
    asm volatile("s_waitcnt lgkmcnt(0)" ::: "memory");
    __builtin_amdgcn_sched_barrier(0);
    __builtin_amdgcn_s_barrier();   // barrier A: buf[cur] fully staged
    __builtin_amdgcn_sched_barrier(0);

    if (kt + 1 < NT) stage_issue(kt + 1);  // overlaps compute below

    f32x4 sc[4];
#pragma unroll
    for (int i = 0; i < 4; i++) sc[i] = (f32x4){0.f, 0.f, 0.f, 0.f};
#pragma unroll
    for (int s = 0; s < 2; s++) {
#pragma unroll
      for (int ks = 0; ks < 4; ks++) {
        s16x8 kf = *(const s16x8*)(Kl + (ks * 16 + lq) * 128 +
                                   (((s * 4 + g) ^ (lq & 7)) << 4));
        sc[ks] = __builtin_amdgcn_mfma_f32_16x16x32_bf16(kf, qf[s], sc[ks],
                                                          0, 0, 0);
      }
    }

    {
      const unsigned mlo = (unsigned)vm, mhi = (unsigned)(vm >> 32);
      const int q_abs = q0 + w * 16 + lq;
      const int qw = q0 + w * 16;
      const bool allin = bandfree || (j0 >= qw - 241 && j0 <= qw + 193);
      const bool fast = (vm == ~0ull) && allin;
      const int ddq = j0 + g * 4 - q_abs;
      const int gsh = g * 4;
      if (fast) {
#pragma unroll
        for (int ks = 0; ks < 4; ks++)
#pragma unroll
          for (int r = 0; r < 4; r++) {
            float p = fexp2(sc[ks][r]);
            sc[ks][r] = p;
            denom += p;
          }
      } else {
#pragma unroll
        for (int ks = 0; ks < 4; ks++)
#pragma unroll
          for (int r = 0; r < 4; r++) {
            float e = fexp2(sc[ks][r]);
            unsigned bit =
                ((ks < 2 ? mlo : mhi) >> (gsh + ((ks & 1) * 16 + r))) & 1u;
            bool ok = bit && (allin ||
                              (unsigned)(ddq + ks * 16 + r + 256) <= 512u);
            float p = ok ? e : 0.f;
            sc[ks][r] = p;
            denom += p;
          }
      }
    }

#pragma unroll
    for (int s = 0; s < 2; s++) {
      const int srcA = lq + ((g & 1) << 5);
      const bool hiSel = g >= 2;
      float L[4], H[4];
#pragma unroll
      for (int r = 0; r < 4; r++) {
        float a0 = __shfl(sc[2 * s][r], srcA);
        float a1 = __shfl(sc[2 * s + 1][r], srcA);
        L[r] = hiSel ? a1 : a0;
        float b0 = __shfl(sc[2 * s][r], srcA + 16);
        float b1 = __shfl(sc[2 * s + 1][r], srcA + 16);
        H[r] = hiSel ? b1 : b0;
      }
      union { unsigned u[4]; s16x8 v; } pf;
      pf.u[0] = pk_bf16(L[0], L[1]);
      pf.u[1] = pk_bf16(L[2], L[3]);
      pf.u[2] = pk_bf16(H[0], H[1]);
      pf.u[3] = pk_bf16(H[2], H[3]);
#pragma unroll
      for (int dblk = 0; dblk < 4; dblk++) {
        s16x8 vf = *(const s16x8*)(VT + (dblk * 16 + lq) * 128 +
                                   (((s * 4 + g) ^ (lq & 7)) << 4));
        oacc[dblk] = __builtin_amdgcn_mfma_f32_16x16x32_bf16(vf, pf.v,
                                                              oacc[dblk],
                                                              0, 0, 0);
      }
    }
    // (barrier B removed — see kernel comment)
  }

  denom += __shfl_xor(denom, 16);
  denom += __shfl_xor(denom, 32);
  const int q_abs = q0 + w * 16 + lq;
  const float rowscale = (amask[b * SS + q_abs] >= 0) ? (1.f / denom) : 0.f;
  u16* orow = ATT + ((size_t)b * SS + q_abs) * DD + h * 64;
#pragma unroll
  for (int dblk = 0; dblk < 4; dblk++) {
    u16x4 o;
#pragma unroll
    for (int r = 0; r < 4; r++) o[r] = f2b(oacc[dblk][r] * rowscale);
    *(u16x4*)(orow + dblk * 16 + g * 4) = o;
  }
}

// ---------------------------------------------------------------------------
// Global-token attention. CHANGE vs R11: 16 splits x 1 tile/wave (grid 384,
// 2x the resident waves), 64 fp32 partials per (b,h).
// ---------------------------------------------------------------------------
__global__ __launch_bounds__(256) void attn_global(
    const u16* __restrict__ Q, const u16* __restrict__ K,
    const u16* __restrict__ V, const int* __restrict__ amask,
    float* __restrict__ Pnum, float* __restrict__ Pden) {
  extern __shared__ __align__(16) char smem[];
  const int tid = threadIdx.x;
  const int w = tid >> 6, lane = tid & 63;
  const int lq = lane & 15, g = lane >> 4;
  const int h = blockIdx.y, b = blockIdx.z;
  const int bh = b * HH + h;
  const size_t bhs = (size_t)bh * SS;
  const int split = (int)blockIdx.x;
  const int j0 = split * 256 + w * 64;

  char* Kl = smem + w * 16384;
  char* VT = Kl + 8192;

  s16x8 qf[2];
  {
    const u16* qp = Q + ((size_t)bh * 16 + lq) * 64;
    qf[0] = *(const s16x8*)(qp + g * 8);
    qf[1] = *(const s16x8*)(qp + 32 + g * 8);
  }

  f32x4 oacc[4];
#pragma unroll
  for (int i = 0; i < 4; i++) oacc[i] = (f32x4){0.f, 0.f, 0.f, 0.f};
  float denom = 0.f;

  int mv = amask[b * SS + j0 + lane];
  unsigned long long vm = __ballot(mv >= 0);

  const u16* Ks = K + bhs * 64 + (size_t)j0 * 64;
#pragma unroll
  for (int i = 0; i < 8; i++) {
    int ci = i * 64 + lane;
    int row = ci >> 3, cc = ci & 7, cs = cc ^ (row & 7);
    load_lds16(Ks + row * 64 + cs * 8, Kl + i * 1024);
  }
  const u16* Vs = V + bhs * 64 + (size_t)j0 * 64;
#pragma unroll
  for (int p = 0; p < 8; p++) {
    u16x8 vv = *(const u16x8*)(Vs + (size_t)lane * 64 + p * 8);
#pragma unroll
    for (int e = 0; e < 8; e++)
      *(u16*)(VT + (p * 8 + e) * 128 + ((lane * 2) ^ (e << 4))) = vv[e];
  }
  asm volatile("s_waitcnt vmcnt(0) lgkmcnt(0)" ::: "memory");

  f32x4 sc[4];
#pragma unroll
  for (int i = 0; i < 4; i++) sc[i] = (f32x4){0.f, 0.f, 0.f, 0.f};
#pragma unroll
  for (int s = 0; s < 2; s++) {
#pragma unroll
    for (int ks = 0; ks < 4; ks++) {
      s16x8 kf = *(const s16x8*)(Kl + (ks * 16 + lq) * 128 +
                                 (((s * 4 + g) ^ (lq & 7)) << 4));
      sc[ks] = __builtin_amdgcn_mfma_f32_16x16x32_bf16(kf, qf[s], sc[ks],
                                                        0, 0, 0);
    }
  }

  {
    const unsigned mlo = (unsigned)vm, mhi = (unsigned)(vm >> 32);
    const bool fast = (vm == ~0ull);
    const int gsh = g * 4;
    if (fast) {
#pragma unroll
      for (int ks = 0; ks < 4; ks++)
#pragma unroll
        for (int r = 0; r < 4; r++) {
          float p = fexp2(sc[ks][r]);
          sc[ks][r] = p;
          denom += p;
        }
    } else {
#pragma unroll
      for (int ks = 0; ks < 4; ks++)
#pragma unroll
        for (int r = 0; r < 4; r++) {
          float e = fexp2(sc[ks][r]);
          unsigned bit =
              ((ks < 2 ? mlo : mhi) >> (gsh + ((ks & 1) * 16 + r))) & 1u;
          float p = bit ? e : 0.f;
          sc[ks][r] = p;
          denom += p;
        }
    }
  }

#pragma unroll
  for (int s = 0; s < 2; s++) {
    const int srcA = lq + ((g & 1) << 5);
    const bool hiSel = g >= 2;
    float L[4], H[4];
#pragma unroll
    for (int r = 0; r < 4; r++) {
      float a0 = __shfl(sc[2 * s][r], srcA);
      float a1 = __shfl(sc[2 * s + 1][r], srcA);
      L[r] = hiSel ? a1 : a0;
      float b0 = __shfl(sc[2 * s][r], srcA + 16);
      float b1 = __shfl(sc[2 * s + 1][r], srcA + 16);
      H[r] = hiSel ? b1 : b0;
    }
    union { unsigned u[4]; s16x8 v; } pf;
    pf.u[0] = pk_bf16(L[0], L[1]);
    pf.u[1] = pk_bf16(L[2], L[3]);
    pf.u[2] = pk_bf16(H[0], H[1]);
    pf.u[3] = pk_bf16(H[2], H[3]);
#pragma unroll
    for (int dblk = 0; dblk < 4; dblk++) {
      s16x8 vf = *(const s16x8*)(VT + (dblk * 16 + lq) * 128 +
                                 (((s * 4 + g) ^ (lq & 7)) << 4));
      oacc[dblk] = __builtin_amdgcn_mfma_f32_16x16x32_bf16(vf, pf.v,
                                                            oacc[dblk],
                                                            0, 0, 0);
    }
  }

  denom += __shfl_xor(denom, 16);
  denom += __shfl_xor(denom, 32);
  const int pidx = split * 4 + w;  // 0..63
  float* np = Pnum + ((size_t)bh * 64 + pidx) * 1024;
#pragma unroll
  for (int dblk = 0; dblk < 4; dblk++)
#pragma unroll
    for (int r = 0; r < 4; r++)
      np[(dblk * 16 + g * 4 + r) * 16 + lq] = oacc[dblk][r];
  Pden[((size_t)bh * 64 + pidx) * 16 + lq] = denom;
}

// ---------------------------------------------------------------------------
// Merge global-token partials (64) and overwrite ATT rows < G.
// ---------------------------------------------------------------------------
__global__ __launch_bounds__(512) void gmerge(const float* __restrict__ Pnum,
                                              const float* __restrict__ Pden,
                                              u16* __restrict__ ATT) {
  const int bh = blockIdx.x;
  const int b = bh / HH, h = bh % HH;
  const int t = threadIdx.x;
  const int q = t >> 6, d = t & 63;
  float num = 0.f, den = 0.f;
#pragma unroll 4
  for (int p = 0; p < 64; p++) {
    num += Pnum[((size_t)bh * 64 + p) * 1024 + d * 16 + q];
    den += Pden[((size_t)bh * 64 + p) * 16 + q];
  }
  ATT[((size_t)b * SS + q) * DD + h * 64 + d] = f2b(num / den);
}

// ---------------------------------------------------------------------------
extern "C" void kernel_launch(void* const* d_in, const int* in_sizes, int n_in,
                              void* d_out, int out_size, void* d_ws,
                              size_t ws_size, hipStream_t stream) {
  const float* hs = (const float*)d_in[0];
  const int* amask = (const int*)d_in[1];
  const float* Wq = (const float*)d_in[2];
  const float* bq = (const float*)d_in[3];
  const float* Wk = (const float*)d_in[4];
  const float* bk = (const float*)d_in[5];
  const float* Wv = (const float*)d_in[6];
  const float* bv = (const float*)d_in[7];
  const float* Wqg = (const float*)d_in[8];
  const float* bqg = (const float*)d_in[9];
  const float* Wkg = (const float*)d_in[10];
  const float* bkg = (const float*)d_in[11];
  const float* Wvg = (const float*)d_in[12];
  const float* bvg = (const float*)d_in[13];
  const float* Wo = (const float*)d_in[14];
  const float* bo = (const float*)d_in[15];
  float* out = (float*)d_out;

  char* ws = (char*)d_ws;
  const size_t QSZB = (size_t)BB * HH * SS * HDD * 2;  // 12582912 B
  u16* Qb = (u16*)(ws + 0);
  u16* Kb = (u16*)(ws + QSZB);
  u16* Vb = (u16*)(ws + 2 * QSZB);
  u16* KGb = (u16*)(ws + 3 * QSZB);
  u16* VGb = (u16*)(ws + 4 * QSZB);
  u16* Ab = (u16*)(ws + 5 * QSZB);
  u16* WTb = (u16*)(ws + 6 * QSZB);                     // 7077888 B
  u16* ATTb = (u16*)(ws + 6 * QSZB + 7077888);          // QSZB
  u16* QGb = (u16*)(ws + 7 * QSZB + 7077888);           // 49152 B
  float* Pnum = (float*)(ws + 7 * QSZB + 7077888 + 49152);   // 6291456 B
  float* Pden = (float*)(ws + 7 * QSZB + 7077888 + 49152 + 6291456);  // 98304

  // 1) fused prep: cvt hs->bf16, transpose weights, qg projection
  WtArgs wa;
  wa.W[0] = Wq; wa.W[1] = Wk; wa.W[2] = Wv;
  wa.W[3] = Wkg; wa.W[4] = Wvg; wa.W[5] = Wo;
  hipLaunchKernelGGL(prep, dim3(3960), dim3(256), 0, stream, hs, wa, Wqg,
                     bqg, Ab, WTb, QGb);

  // 2) fused projections (bf16 MFMA, 8-phase 256x256, coalesced epilogue)
  BiasArgs b0;
  b0.bias[0] = bq; b0.bias[1] = bk; b0.bias[2] = bv;
  b0.bias[3] = bkg; b0.bias[4] = bvg;
  hipLaunchKernelGGL(gemm0_8p, dim3(480), dim3(512), 135168, stream, Ab,
                     WTb, b0, Qb);

  // 3) global-token attention partials (16 splits, 1 tile/wave)
  hipLaunchKernelGGL(attn_global, dim3(16, HH, BB), dim3(256), 65536, stream,
                     QGb, KGb, VGb, amask, Pnum, Pden);

  // 4) banded attention -> ATT (bf16), pipelined 128-query WGs
  hipLaunchKernelGGL(attn_band, dim3(32, HH, BB), dim3(512), 0, stream, Qb,
                     Kb, Vb, amask, ATTb);

  // 5) merge global-token rows into ATT
  hipLaunchKernelGGL(gmerge, dim3(24), dim3(512), 0, stream, Pnum, Pden, ATTb);

  // 6) output projection (bf16 MFMA, fp32 out, coalesced epilogue)
  BiasArgs b1;
  for (int i = 0; i < 5; i++) b1.bias[i] = bo;
  hipLaunchKernelGGL((gemm_bf16<1>), dim3(192), dim3(512), 147456, stream,
                     ATTb, WTb + (size_t)5 * 768 * 768, b1, (u16*)nullptr,
                     out);
}

// Round 13
// 186.328 us; speedup vs baseline: 1.0360x; 1.0360x over previous
//
#include <hip/hip_runtime.h>

#define BB 2
#define SS 4096
#define DD 768
#define HH 12
#define HDD 64
#define W1C 256
#define NCC 16
#define GG 8

typedef unsigned short u16;
typedef __attribute__((ext_vector_type(4))) unsigned short u16x4;
typedef __attribute__((ext_vector_type(8))) unsigned short u16x8;
typedef __attribute__((ext_vector_type(8))) short s16x8;
typedef __attribute__((ext_vector_type(4))) float f32x4;

__device__ __forceinline__ float b2f(u16 u) {
  union { unsigned int i; float f; } v;
  v.i = ((unsigned int)u) << 16;
  return v.f;
}
__device__ __forceinline__ u16 f2b(float f) {
  union { float f; unsigned int i; } v;
  v.f = f;
  unsigned int r = v.i + 0x7FFFu + ((v.i >> 16) & 1u);
  return (u16)(r >> 16);
}
__device__ __forceinline__ float fexp2(float x) {
#if __has_builtin(__builtin_amdgcn_exp2f)
  return __builtin_amdgcn_exp2f(x);
#else
  return exp2f(x);
#endif
}
__device__ __forceinline__ unsigned pk_bf16(float lo, float hi) {
  unsigned r;
  asm("v_cvt_pk_bf16_f32 %0, %1, %2" : "=v"(r) : "v"(lo), "v"(hi));
  return r;
}
__device__ __forceinline__ void load_lds16(const void* g, void* l) {
  __builtin_amdgcn_global_load_lds(
      (const __attribute__((address_space(1))) unsigned int*)g,
      (__attribute__((address_space(3))) unsigned int*)l, 16, 0, 0);
}

#define QSCALE 0.18033688011112042f  // 0.125 * log2(e)

// ---------------------------------------------------------------------------
// Fused prep: blockIdx dispatch. (unchanged)
// ---------------------------------------------------------------------------
struct WtArgs { const float* W[6]; };

__global__ __launch_bounds__(256) void prep(
    const float* __restrict__ hs, WtArgs wa, const float* __restrict__ Wqg,
    const float* __restrict__ bqg, u16* __restrict__ Ab,
    u16* __restrict__ WT, u16* __restrict__ QG) {
  __shared__ __align__(16) char pshm[24576];
  const int bid = blockIdx.x;
  const int t = threadIdx.x;

  if (bid < 3072) {
    int i = bid * 256 + t;
    const float4* p = (const float4*)(hs + (size_t)i * 8);
    float4 a = p[0], b = p[1];
    u16x8 o;
    o[0] = f2b(a.x); o[1] = f2b(a.y); o[2] = f2b(a.z); o[3] = f2b(a.w);
    o[4] = f2b(b.x); o[5] = f2b(b.y); o[6] = f2b(b.z); o[7] = f2b(b.w);
    *(u16x8*)(Ab + (size_t)i * 8) = o;
  } else if (bid < 3936) {
    float (*T)[65] = (float (*)[65])pshm;
    const int t2 = bid - 3072;
    const int mat = t2 / 144;
    const int rem = t2 % 144;
    const int k0 = (rem / 12) * 64;
    const int n0 = (rem % 12) * 64;
    const float* __restrict__ W = wa.W[mat];
#pragma unroll
    for (int i = 0; i < 4; i++) {
      int idx4 = t + i * 256;
      int r = idx4 >> 4, c4 = idx4 & 15;
      float4 v = *(const float4*)(W + (size_t)(k0 + r) * 768 + n0 + c4 * 4);
      T[r][c4 * 4 + 0] = v.x; T[r][c4 * 4 + 1] = v.y;
      T[r][c4 * 4 + 2] = v.z; T[r][c4 * 4 + 3] = v.w;
    }
    __syncthreads();
#pragma unroll
    for (int i = 0; i < 2; i++) {
      int ci = t + i * 256;
      int nl = ci >> 3, k8 = ci & 7;
      u16x8 o;
#pragma unroll
      for (int jj = 0; jj < 8; jj++) o[jj] = f2b(T[k8 * 8 + jj][nl]);
      *(u16x8*)(WT + ((size_t)mat * 768 + n0 + nl) * 768 + k0 + k8 * 8) = o;
    }
  } else {
    float (*hsL)[768] = (float (*)[768])pshm;
    const int bh = bid - 3936;
    const int b = bh / HH, h = bh % HH;
#pragma unroll
    for (int i = 0; i < 6; i++) {
      int idx = t + i * 256;
      int row = idx / 192, c4 = idx % 192;
      *(float4*)&hsL[row][c4 * 4] =
          *(const float4*)(hs + ((size_t)b * SS + row) * DD + c4 * 4);
    }
    __syncthreads();
#pragma unroll
    for (int rep = 0; rep < 2; rep++) {
      int qi = rep * 4 + (t >> 6);
      int d = t & 63, n = h * 64 + d;
      float acc = bqg[n];
      for (int k = 0; k < DD; k++)
        acc = fmaf(hsL[qi][k], Wqg[(size_t)k * DD + n], acc);
      QG[((size_t)bh * 16 + qi) * 64 + d] = f2b(acc * QSCALE);
    }
#pragma unroll
    for (int i = 0; i < 2; i++) {
      int idx = t + i * 256;
      int row = 8 + (idx >> 6), d = idx & 63;
      QG[((size_t)bh * 16 + row) * 64 + d] = 0;
    }
  }
}

struct BiasArgs { const float* bias[5]; };

// ---------------------------------------------------------------------------
// 8-phase 256x256 bf16 MFMA GEMM + coalesced LDS epilogue. (unchanged R11)
// ---------------------------------------------------------------------------
__global__ __launch_bounds__(512, 1) void gemm0_8p(
    const u16* __restrict__ A, const u16* __restrict__ WT, BiasArgs ba,
    u16* __restrict__ outb) {
  constexpr int NTL = 15;
  constexpr int NWG = 480;
  constexpr int NT = 12;
  constexpr int TBYTES = 256 * 64 * 2;
  constexpr int BUFB = 2 * TBYTES;
  constexpr int EPAD = 264;

  extern __shared__ __align__(16) char smem[];

  const int tid = threadIdx.x;
  const int w = tid >> 6, l = tid & 63;
  const int lq = l & 15, g = l >> 4;
  const int wm = w >> 2, wn = w & 3;

  const int cpx = NWG >> 3;
  const int id = (int)blockIdx.x;
  const int swz = (id & 7) * cpx + (id >> 3);
  const int bm = swz / NTL, bn = swz % NTL;
  const int m0 = bm * 256;
  const int nw0 = bn * 256;
  const int wsel = bn / 3;
  const int nmat0 = (bn % 3) * 256;
  const float* __restrict__ bias = ba.bias[wsel];

  f32x4 acc[8][4];
#pragma unroll
  for (int i = 0; i < 8; i++)
#pragma unroll
    for (int j = 0; j < 4; j++) acc[i][j] = (f32x4){0.f, 0.f, 0.f, 0.f};

  auto stageH = [&](int t, int mat, int h) {
    const int k0 = t * 64;
    char* dst = smem + (t & 1) * BUFB + mat * TBYTES + h * 16384;
    const u16* src = mat ? WT : A;
    const int rbase = (mat ? nw0 : m0) + h * 128;
#pragma unroll
    for (int j = 0; j < 2; j++) {
      const int p = (j * 8 + w) * 64 + l;
      const int row = p >> 3, sl = p & 7;
      load_lds16(src + (size_t)(rbase + row) * 768 + k0 +
                     ((sl ^ (row & 7)) * 8),
                 dst + (j * 8 + w) * 1024);
    }
  };

  stageH(0, 0, 0); stageH(0, 0, 1); stageH(0, 1, 0); stageH(0, 1, 1);
  stageH(1, 0, 0);
  asm volatile("s_waitcnt vmcnt(2)" ::: "memory");
  __builtin_amdgcn_sched_barrier(0);
  __builtin_amdgcn_s_barrier();
  __builtin_amdgcn_sched_barrier(0);

  s16x8 bf[4];

  for (int kt = 0; kt < NT; kt++) {
    const u16* rA = (const u16*)(smem + (kt & 1) * BUFB);
    const u16* rB = (const u16*)(smem + (kt & 1) * BUFB + TBYTES);

#pragma unroll
    for (int ph = 0; ph < 4; ph++) {
      const int mh = ph & 1;
      const int kh = ph >> 1;
      s16x8 af[4];
#pragma unroll
      for (int mi = 0; mi < 4; mi++) {
        const int r = wm * 128 + (mh * 4 + mi) * 16 + lq;
        af[mi] =
            *(const s16x8*)(rA + r * 64 + (((kh * 4 + g) ^ (r & 7)) * 8));
      }
      if (mh == 0) {
#pragma unroll
        for (int nj = 0; nj < 4; nj++) {
          const int r = wn * 64 + nj * 16 + lq;
          bf[nj] =
              *(const s16x8*)(rB + r * 64 + (((kh * 4 + g) ^ (r & 7)) * 8));
        }
      }
      if (ph == 0) { if (kt + 1 < NT) stageH(kt + 1, 0, 1); }
      else if (ph == 1) { if (kt + 1 < NT) stageH(kt + 1, 1, 0); }
      else if (ph == 2) { if (kt + 1 < NT) stageH(kt + 1, 1, 1); }
      else { if (kt + 2 < NT) stageH(kt + 2, 0, 0); }

      __builtin_amdgcn_s_barrier();
      asm volatile("s_waitcnt lgkmcnt(0)" ::: "memory");
      __builtin_amdgcn_sched_barrier(0);
      __builtin_amdgcn_s_setprio(1);
#pragma unroll
      for (int mi = 0; mi < 4; mi++)
#pragma unroll
        for (int nj = 0; nj < 4; nj++)
          acc[mh * 4 + mi][nj] = __builtin_amdgcn_mfma_f32_16x16x32_bf16(
              af[mi], bf[nj], acc[mh * 4 + mi][nj], 0, 0, 0);
      __builtin_amdgcn_s_setprio(0);

      if (ph == 3) {
        if (kt < NT - 2)
          asm volatile("s_waitcnt vmcnt(2)" ::: "memory");
        else
          asm volatile("s_waitcnt vmcnt(0)" ::: "memory");
      }
      __builtin_amdgcn_sched_barrier(0);
      __builtin_amdgcn_s_barrier();
      __builtin_amdgcn_sched_barrier(0);
    }
  }

  {
    const float scale = (wsel == 0) ? QSCALE : 1.0f;
    u16* T = (u16*)smem;
#pragma unroll
    for (int nj = 0; nj < 4; nj++) {
      const int cl = wn * 64 + nj * 16 + lq;
      const float bv = bias[nmat0 + cl];
#pragma unroll
      for (int mi = 0; mi < 8; mi++) {
#pragma unroll
        for (int r = 0; r < 4; r++) {
          const int ml = wm * 128 + mi * 16 + g * 4 + r;
          T[ml * EPAD + cl] = f2b((acc[mi][nj][r] + bv) * scale);
        }
      }
    }
    __syncthreads();
    u16* outw = outb + (size_t)wsel * ((size_t)BB * HH * SS * HDD);
    const int b = m0 >> 12;
    const int sbase = m0 & 4095;
    const int hbase = nmat0 >> 6;
#pragma unroll
    for (int j = 0; j < 16; j++) {
      const int slot = j * 512 + tid;
      const int seg = slot >> 3, part = slot & 7;
      const int h = seg >> 8, sl = seg & 255;
      u16x8 v = *(const u16x8*)(T + sl * EPAD + h * 64 + part * 8);
      *(u16x8*)(outw +
                ((size_t)(b * HH + hbase + h) * SS + sbase + sl) * HDD +
                part * 8) = v;
    }
  }
}

// ---------------------------------------------------------------------------
// Wo GEMM: BM=128 x BN=192, grid 256 (= exactly 1 block/CU, full coverage).
// 3-buffer LDS ring (40KB/buf), 8 waves (2M x 4N), wave tile 64x48, BK=64,
// counted vmcnt(5). Coalesced fp32 epilogue via [128][196] LDS tile.
// ---------------------------------------------------------------------------
__global__ __launch_bounds__(512, 1) void gemm1(
    const u16* __restrict__ A, const u16* __restrict__ WT, const float* bias,
    float* __restrict__ outf) {
  constexpr int NTL = 4;                      // n-tiles of 192
  constexpr int NWG = 256;
  constexpr int NT = 12;
  constexpr int ABYTES = 128 * 64 * 2;        // 16384
  constexpr int BBYTES = 192 * 64 * 2;        // 24576
  constexpr int BUFB = ABYTES + BBYTES;       // 40960; x3 = 122880
  constexpr int EPADF = 196;

  extern __shared__ __align__(16) char smem[];

  const int tid = threadIdx.x;
  const int w = tid >> 6, l = tid & 63;
  const int lq = l & 15, g = l >> 4;
  const int wm = w >> 2, wn = w & 3;

  const int cpx = NWG >> 3;
  const int id = (int)blockIdx.x;
  const int swz = (id & 7) * cpx + (id >> 3);
  const int bm = swz / NTL, bn = swz % NTL;
  const int m0 = bm * 128;
  const int nw0 = bn * 192;
  const int nmat0 = bn * 192;

  f32x4 acc[4][3];
#pragma unroll
  for (int i = 0; i < 4; i++)
#pragma unroll
    for (int j = 0; j < 3; j++) acc[i][j] = (f32x4){0.f, 0.f, 0.f, 0.f};

  auto stage = [&](int t) {
    const int k0 = t * 64;
    char* uA = smem + (t % 3) * BUFB;
    char* uB = uA + ABYTES;
#pragma unroll
    for (int j = 0; j < 2; j++) {       // A: 16 x 1KB chunks
      const int p = j * 512 + tid;
      const int row = p >> 3, sl = p & 7;
      load_lds16(A + (size_t)(m0 + row) * 768 + k0 + ((sl ^ (row & 7)) * 8),
                 uA + (j * 8 + w) * 1024);
    }
#pragma unroll
    for (int j = 0; j < 3; j++) {       // B: 24 x 1KB chunks (192 rows)
      const int p = j * 512 + tid;
      const int row = p >> 3, sl = p & 7;
      load_lds16(WT + (size_t)(nw0 + row) * 768 + k0 + ((sl ^ (row & 7)) * 8),
                 uB + (j * 8 + w) * 1024);
    }
  };

  stage(0);
  stage(1);
  asm volatile("s_waitcnt vmcnt(5)" ::: "memory");
  __builtin_amdgcn_sched_barrier(0);
  __builtin_amdgcn_s_barrier();
  __builtin_amdgcn_sched_barrier(0);

  for (int kt = 0; kt < NT; kt++) {
    const u16* rA = (const u16*)(smem + (kt % 3) * BUFB);
    const u16* rB = (const u16*)(smem + (kt % 3) * BUFB + ABYTES);

    if (kt < NT - 2) stage(kt + 2);
    __builtin_amdgcn_sched_barrier(0);

    s16x8 af[4][2], bf[3][2];
#pragma unroll
    for (int mi = 0; mi < 4; mi++) {
      const int r = wm * 64 + mi * 16 + lq;
#pragma unroll
      for (int ks = 0; ks < 2; ks++)
        af[mi][ks] =
            *(const s16x8*)(rA + r * 64 + (((ks * 4 + g) ^ (r & 7)) * 8));
    }
#pragma unroll
    for (int nj = 0; nj < 3; nj++) {
      const int r = wn * 48 + nj * 16 + lq;
#pragma unroll
      for (int ks = 0; ks < 2; ks++)
        bf[nj][ks] =
            *(const s16x8*)(rB + r * 64 + (((ks * 4 + g) ^ (r & 7)) * 8));
    }
#pragma unroll
    for (int mi = 0; mi < 4; mi++)
#pragma unroll
      for (int nj = 0; nj < 3; nj++)
#pragma unroll
        for (int ks = 0; ks < 2; ks++)
          acc[mi][nj] = __builtin_amdgcn_mfma_f32_16x16x32_bf16(
              af[mi][ks], bf[nj][ks], acc[mi][nj], 0, 0, 0);

    if (kt < NT - 2)
      asm volatile("s_waitcnt vmcnt(5)" ::: "memory");
    else
      asm volatile("s_waitcnt vmcnt(0)" ::: "memory");
    __builtin_amdgcn_sched_barrier(0);
    __builtin_amdgcn_s_barrier();
    __builtin_amdgcn_sched_barrier(0);
  }

  // coalesced fp32 epilogue
  {
    float* Tf = (float*)smem;
#pragma unroll
    for (int nj = 0; nj < 3; nj++) {
      const int cl = wn * 48 + nj * 16 + lq;
      const float bv = bias[nmat0 + cl];
#pragma unroll
      for (int mi = 0; mi < 4; mi++) {
#pragma unroll
        for (int r = 0; r < 4; r++) {
          const int ml = wm * 64 + mi * 16 + g * 4 + r;
          Tf[ml * EPADF + cl] = acc[mi][nj][r] + bv;
        }
      }
    }
    __syncthreads();
#pragma unroll
    for (int j = 0; j < 12; j++) {
      const int slot = j * 512 + tid;       // 6144 float4 = 128 x 48
      const int row = slot / 48, part = slot % 48;
      float4 v = *(const float4*)(Tf + row * EPADF + part * 4);
      *(float4*)(outf + (size_t)(m0 + row) * 768 + nmat0 + part * 4) = v;
    }
  }
}

// ---------------------------------------------------------------------------
// Banded MFMA attention, pipelined (R11 exact — both barriers).
// ---------------------------------------------------------------------------
__global__ __launch_bounds__(512, 4) void attn_band(
    const u16* __restrict__ Q, const u16* __restrict__ K,
    const u16* __restrict__ V, const int* __restrict__ amask,
    u16* __restrict__ ATT) {
  __shared__ __align__(16) char smem[32768];
  const int tid = threadIdx.x;
  const int w = tid >> 6, lane = tid & 63;
  const int lq = lane & 15, g = lane >> 4;
  const int h = blockIdx.y, b = blockIdx.z;
  const int bh = b * HH + h;
  const size_t bhs = (size_t)bh * SS;
  const int q0 = (int)blockIdx.x * 128;

  s16x8 qf[2];
  {
    const u16* qp = Q + (bhs + q0 + w * 16 + lq) * 64;
    qf[0] = *(const s16x8*)(qp + g * 8);
    qf[1] = *(const s16x8*)(qp + 32 + g * 8);
  }

  f32x4 oacc[4];
#pragma unroll
  for (int i = 0; i < 4; i++) oacc[i] = (f32x4){0.f, 0.f, 0.f, 0.f};
  float denom = 0.f;

  const int NT = 11;
  u16x8 vreg;

  auto jof = [&](int t) { return t < 10 ? q0 - 256 + t * 64 : 0; };

  auto stage_issue = [&](int t) {
    const int j0 = jof(t);
    char* Kb_ = smem + (t & 1) * 16384;
    const int row = tid >> 3, sl = tid & 7;
    if (j0 >= 0 && j0 + 64 <= SS) {
      load_lds16(K + (bhs + j0 + row) * 64 + ((sl ^ (row & 7)) * 8),
                 Kb_ + w * 1024);
    } else {
      int jj = j0 + row;
      u16x8 val;
#pragma unroll
      for (int e = 0; e < 8; e++) val[e] = 0;
      if ((unsigned)jj < (unsigned)SS)
        val = *(const u16x8*)(K + (bhs + jj) * 64 + ((sl ^ (row & 7)) * 8));
      *(u16x8*)(Kb_ + tid * 16) = val;
    }
    int jj = j0 + lane;
    u16x8 vv;
#pragma unroll
    for (int e = 0; e < 8; e++) vv[e] = 0;
    if ((unsigned)jj < (unsigned)SS)
      vv = *(const u16x8*)(V + (bhs + jj) * 64 + w * 8);
    vreg = vv;
  };

  stage_issue(0);

  for (int kt = 0; kt < NT; kt++) {
    const int j0 = jof(kt);
    const int cur = kt & 1;
    char* Kl = smem + cur * 16384;
    char* VT = Kl + 8192;
    const bool bandfree = (kt == 10);
    const int klimit = bandfree ? 8 : 64;

    int jm = j0 + lane;
    int mv = ((unsigned)jm < (unsigned)SS) ? amask[b * SS + jm] : -1;
    bool okk = (mv >= 0) && (lane < klimit);
    unsigned long long vm = __ballot(okk);

    asm volatile("s_waitcnt vmcnt(0)" ::: "memory");
#pragma unroll
    for (int e = 0; e < 8; e++)
      *(u16*)(VT + (w * 8 + e) * 128 + ((lane * 2) ^ (e << 4))) = vreg[e];
    asm volatile("s_waitcnt lgkmcnt(0)" ::: "memory");
    __builtin_amdgcn_sched_barrier(0);
    __builtin_amdgcn_s_barrier();   // barrier A: buf[cur] fully staged
    __builtin_amdgcn_sched_barrier(0);

    if (kt + 1 < NT) stage_issue(kt + 1);

    f32x4 sc[4];
#pragma unroll
    for (int i = 0; i < 4; i++) sc[i] = (f32x4){0.f, 0.f, 0.f, 0.f};
#pragma unroll
    for (int s = 0; s < 2; s++) {
#pragma unroll
      for (int ks = 0; ks < 4; ks++) {
        s16x8 kf = *(const s16x8*)(Kl + (ks * 16 + lq) * 128 +
                                   (((s * 4 + g) ^ (lq & 7)) << 4));
        sc[ks] = __builtin_amdgcn_mfma_f32_16x16x32_bf16(kf, qf[s], sc[ks],
                                                          0, 0, 0);
      }
    }

    {
      const unsigned mlo = (unsigned)vm, mhi = (unsigned)(vm >> 32);
      const int q_abs = q0 + w * 16 + lq;
      const int qw = q0 + w * 16;
      const bool allin = bandfree || (j0 >= qw - 241 && j0 <= qw + 193);
      const bool fast = (vm == ~0ull) && allin;
      const int ddq = j0 + g * 4 - q_abs;
      const int gsh = g * 4;
      if (fast) {
#pragma unroll
        for (int ks = 0; ks < 4; ks++)
#pragma unroll
          for (int r = 0; r < 4; r++) {
            float p = fexp2(sc[ks][r]);
            sc[ks][r] = p;
            denom += p;
          }
      } else {
#pragma unroll
        for (int ks = 0; ks < 4; ks++)
#pragma unroll
          for (int r = 0; r < 4; r++) {
            float e = fexp2(sc[ks][r]);
            unsigned bit =
                ((ks < 2 ? mlo : mhi) >> (gsh + ((ks & 1) * 16 + r))) & 1u;
            bool ok = bit && (allin ||
                              (unsigned)(ddq + ks * 16 + r + 256) <= 512u);
            float p = ok ? e : 0.f;
            sc[ks][r] = p;
            denom += p;
          }
      }
    }

#pragma unroll
    for (int s = 0; s < 2; s++) {
      const int srcA = lq + ((g & 1) << 5);
      const bool hiSel = g >= 2;
      float L[4], H[4];
#pragma unroll
      for (int r = 0; r < 4; r++) {
        float a0 = __shfl(sc[2 * s][r], srcA);
        float a1 = __shfl(sc[2 * s + 1][r], srcA);
        L[r] = hiSel ? a1 : a0;
        float b0 = __shfl(sc[2 * s][r], srcA + 16);
        float b1 = __shfl(sc[2 * s + 1][r], srcA + 16);
        H[r] = hiSel ? b1 : b0;
      }
      union { unsigned u[4]; s16x8 v; } pf;
      pf.u[0] = pk_bf16(L[0], L[1]);
      pf.u[1] = pk_bf16(L[2], L[3]);
      pf.u[2] = pk_bf16(H[0], H[1]);
      pf.u[3] = pk_bf16(H[2], H[3]);
#pragma unroll
      for (int dblk = 0; dblk < 4; dblk++) {
        s16x8 vf = *(const s16x8*)(VT + (dblk * 16 + lq) * 128 +
                                   (((s * 4 + g) ^ (lq & 7)) << 4));
        oacc[dblk] = __builtin_amdgcn_mfma_f32_16x16x32_bf16(vf, pf.v,
                                                              oacc[dblk],
                                                              0, 0, 0);
      }
    }

    __builtin_amdgcn_sched_barrier(0);
    __builtin_amdgcn_s_barrier();   // barrier B: buf[cur] reads done
    __builtin_amdgcn_sched_barrier(0);
  }

  denom += __shfl_xor(denom, 16);
  denom += __shfl_xor(denom, 32);
  const int q_abs = q0 + w * 16 + lq;
  const float rowscale = (amask[b * SS + q_abs] >= 0) ? (1.f / denom) : 0.f;
  u16* orow = ATT + ((size_t)b * SS + q_abs) * DD + h * 64;
#pragma unroll
  for (int dblk = 0; dblk < 4; dblk++) {
    u16x4 o;
#pragma unroll
    for (int r = 0; r < 4; r++) o[r] = f2b(oacc[dblk][r] * rowscale);
    *(u16x4*)(orow + dblk * 16 + g * 4) = o;
  }
}

// ---------------------------------------------------------------------------
// Global-token attention (R11 exact): 8 splits x 2 tiles/wave, 32 partials.
// ---------------------------------------------------------------------------
__global__ __launch_bounds__(256) void attn_global(
    const u16* __restrict__ Q, const u16* __restrict__ K,
    const u16* __restrict__ V, const int* __restrict__ amask,
    float* __restrict__ Pnum, float* __restrict__ Pden) {
  extern __shared__ __align__(16) char smem[];
  const int tid = threadIdx.x;
  const int w = tid >> 6, lane = tid & 63;
  const int lq = lane & 15, g = lane >> 4;
  const int h = blockIdx.y, b = blockIdx.z;
  const int bh = b * HH + h;
  const size_t bhs = (size_t)bh * SS;
  const int split = (int)blockIdx.x;

  char* Kl = smem + w * 16384;
  char* VT = Kl + 8192;

  s16x8 qf[2];
  {
    const u16* qp = Q + ((size_t)bh * 16 + lq) * 64;
    qf[0] = *(const s16x8*)(qp + g * 8);
    qf[1] = *(const s16x8*)(qp + 32 + g * 8);
  }

  f32x4 oacc[4];
#pragma unroll
  for (int i = 0; i < 4; i++) oacc[i] = (f32x4){0.f, 0.f, 0.f, 0.f};
  float denom = 0.f;

  for (int kt = 0; kt < 2; kt++) {
    const int j0 = split * 512 + (w * 2 + kt) * 64;

    int jm = j0 + lane;
    int mv = amask[b * SS + jm];
    unsigned long long vm = __ballot(mv >= 0);

    asm volatile("s_waitcnt lgkmcnt(0)" ::: "memory");
    const u16* Ks = K + bhs * 64 + (size_t)j0 * 64;
#pragma unroll
    for (int i = 0; i < 8; i++) {
      int ci = i * 64 + lane;
      int row = ci >> 3, cc = ci & 7, cs = cc ^ (row & 7);
      load_lds16(Ks + row * 64 + cs * 8, Kl + i * 1024);
    }
    const u16* Vs = V + bhs * 64 + (size_t)j0 * 64;
#pragma unroll
    for (int p = 0; p < 8; p++) {
      u16x8 vv = *(const u16x8*)(Vs + (size_t)lane * 64 + p * 8);
#pragma unroll
      for (int e = 0; e < 8; e++)
        *(u16*)(VT + (p * 8 + e) * 128 + ((lane * 2) ^ (e << 4))) = vv[e];
    }
    asm volatile("s_waitcnt vmcnt(0) lgkmcnt(0)" ::: "memory");

    f32x4 sc[4];
#pragma unroll
    for (int i = 0; i < 4; i++) sc[i] = (f32x4){0.f, 0.f, 0.f, 0.f};
#pragma unroll
    for (int s = 0; s < 2; s++) {
#pragma unroll
      for (int ks = 0; ks < 4; ks++) {
        s16x8 kf = *(const s16x8*)(Kl + (ks * 16 + lq) * 128 +
                                   (((s * 4 + g) ^ (lq & 7)) << 4));
        sc[ks] = __builtin_amdgcn_mfma_f32_16x16x32_bf16(kf, qf[s], sc[ks],
                                                          0, 0, 0);
      }
    }

    {
      const unsigned mlo = (unsigned)vm, mhi = (unsigned)(vm >> 32);
      const bool fast = (vm == ~0ull);
      const int gsh = g * 4;
      if (fast) {
#pragma unroll
        for (int ks = 0; ks < 4; ks++)
#pragma unroll
          for (int r = 0; r < 4; r++) {
            float p = fexp2(sc[ks][r]);
            sc[ks][r] = p;
            denom += p;
          }
      } else {
#pragma unroll
        for (int ks = 0; ks < 4; ks++)
#pragma unroll
          for (int r = 0; r < 4; r++) {
            float e = fexp2(sc[ks][r]);
            unsigned bit =
                ((ks < 2 ? mlo : mhi) >> (gsh + ((ks & 1) * 16 + r))) & 1u;
            float p = bit ? e : 0.f;
            sc[ks][r] = p;
            denom += p;
          }
      }
    }

#pragma unroll
    for (int s = 0; s < 2; s++) {
      const int srcA = lq + ((g & 1) << 5);
      const bool hiSel = g >= 2;
      float L[4], H[4];
#pragma unroll
      for (int r = 0; r < 4; r++) {
        float a0 = __shfl(sc[2 * s][r], srcA);
        float a1 = __shfl(sc[2 * s + 1][r], srcA);
        L[r] = hiSel ? a1 : a0;
        float b0 = __shfl(sc[2 * s][r], srcA + 16);
        float b1 = __shfl(sc[2 * s + 1][r], srcA + 16);
        H[r] = hiSel ? b1 : b0;
      }
      union { unsigned u[4]; s16x8 v; } pf;
      pf.u[0] = pk_bf16(L[0], L[1]);
      pf.u[1] = pk_bf16(L[2], L[3]);
      pf.u[2] = pk_bf16(H[0], H[1]);
      pf.u[3] = pk_bf16(H[2], H[3]);
#pragma unroll
      for (int dblk = 0; dblk < 4; dblk++) {
        s16x8 vf = *(const s16x8*)(VT + (dblk * 16 + lq) * 128 +
                                   (((s * 4 + g) ^ (lq & 7)) << 4));
        oacc[dblk] = __builtin_amdgcn_mfma_f32_16x16x32_bf16(vf, pf.v,
                                                              oacc[dblk],
                                                              0, 0, 0);
      }
    }
  }

  denom += __shfl_xor(denom, 16);
  denom += __shfl_xor(denom, 32);
  const int pidx = split * 4 + w;
  float* np = Pnum + ((size_t)bh * 32 + pidx) * 1024;
#pragma unroll
  for (int dblk = 0; dblk < 4; dblk++)
#pragma unroll
    for (int r = 0; r < 4; r++)
      np[(dblk * 16 + g * 4 + r) * 16 + lq] = oacc[dblk][r];
  Pden[((size_t)bh * 32 + pidx) * 16 + lq] = denom;
}

// ---------------------------------------------------------------------------
// Merge global-token partials (32) and overwrite ATT rows < G.
// ---------------------------------------------------------------------------
__global__ __launch_bounds__(512) void gmerge(const float* __restrict__ Pnum,
                                              const float* __restrict__ Pden,
                                              u16* __restrict__ ATT) {
  const int bh = blockIdx.x;
  const int b = bh / HH, h = bh % HH;
  const int t = threadIdx.x;
  const int q = t >> 6, d = t & 63;
  float num = 0.f, den = 0.f;
#pragma unroll 4
  for (int p = 0; p < 32; p++) {
    num += Pnum[((size_t)bh * 32 + p) * 1024 + d * 16 + q];
    den += Pden[((size_t)bh * 32 + p) * 16 + q];
  }
  ATT[((size_t)b * SS + q) * DD + h * 64 + d] = f2b(num / den);
}

// ---------------------------------------------------------------------------
extern "C" void kernel_launch(void* const* d_in, const int* in_sizes, int n_in,
                              void* d_out, int out_size, void* d_ws,
                              size_t ws_size, hipStream_t stream) {
  const float* hs = (const float*)d_in[0];
  const int* amask = (const int*)d_in[1];
  const float* Wq = (const float*)d_in[2];
  const float* bq = (const float*)d_in[3];
  const float* Wk = (const float*)d_in[4];
  const float* bk = (const float*)d_in[5];
  const float* Wv = (const float*)d_in[6];
  const float* bv = (const float*)d_in[7];
  const float* Wqg = (const float*)d_in[8];
  const float* bqg = (const float*)d_in[9];
  const float* Wkg = (const float*)d_in[10];
  const float* bkg = (const float*)d_in[11];
  const float* Wvg = (const float*)d_in[12];
  const float* bvg = (const float*)d_in[13];
  const float* Wo = (const float*)d_in[14];
  const float* bo = (const float*)d_in[15];
  float* out = (float*)d_out;

  char* ws = (char*)d_ws;
  const size_t QSZB = (size_t)BB * HH * SS * HDD * 2;  // 12582912 B
  u16* Qb = (u16*)(ws + 0);
  u16* Kb = (u16*)(ws + QSZB);
  u16* Vb = (u16*)(ws + 2 * QSZB);
  u16* KGb = (u16*)(ws + 3 * QSZB);
  u16* VGb = (u16*)(ws + 4 * QSZB);
  u16* Ab = (u16*)(ws + 5 * QSZB);
  u16* WTb = (u16*)(ws + 6 * QSZB);                     // 7077888 B
  u16* ATTb = (u16*)(ws + 6 * QSZB + 7077888);          // QSZB
  u16* QGb = (u16*)(ws + 7 * QSZB + 7077888);           // 49152 B
  float* Pnum = (float*)(ws + 7 * QSZB + 7077888 + 49152);   // 3145728 B
  float* Pden = (float*)(ws + 7 * QSZB + 7077888 + 49152 + 3145728);  // 49152

  // 1) fused prep: cvt hs->bf16, transpose weights, qg projection
  WtArgs wa;
  wa.W[0] = Wq; wa.W[1] = Wk; wa.W[2] = Wv;
  wa.W[3] = Wkg; wa.W[4] = Wvg; wa.W[5] = Wo;
  hipLaunchKernelGGL(prep, dim3(3960), dim3(256), 0, stream, hs, wa, Wqg,
                     bqg, Ab, WTb, QGb);

  // 2) fused projections (bf16 MFMA, 8-phase 256x256, coalesced epilogue)
  BiasArgs b0;
  b0.bias[0] = bq; b0.bias[1] = bk; b0.bias[2] = bv;
  b0.bias[3] = bkg; b0.bias[4] = bvg;
  hipLaunchKernelGGL(gemm0_8p, dim3(480), dim3(512), 135168, stream, Ab,
                     WTb, b0, Qb);

  // 3) global-token attention partials (8 splits x 2 tiles/wave)
  hipLaunchKernelGGL(attn_global, dim3(8, HH, BB), dim3(256), 65536, stream,
                     QGb, KGb, VGb, amask, Pnum, Pden);

  // 4) banded attention -> ATT (bf16), pipelined 128-query WGs
  hipLaunchKernelGGL(attn_band, dim3(32, HH, BB), dim3(512), 0, stream, Qb,
                     Kb, Vb, amask, ATTb);

  // 5) merge global-token rows into ATT
  hipLaunchKernelGGL(gmerge, dim3(24), dim3(512), 0, stream, Pnum, Pden, ATTb);

  // 6) output projection (BM128xBN192, grid 256 = full CU coverage)
  hipLaunchKernelGGL(gemm1, dim3(256), dim3(512), 122880, stream, ATTb,
                     WTb + (size_t)5 * 768 * 768, bo, out);
}